// Round 6
// baseline (350.203 us; speedup 1.0000x reference)
//
#include <hip/hip_runtime.h>

#define NN 100000
#define NE 1000000
#define IND 128
#define OUTD 64
#define KST 4
#define NBLK ((NN + 255) / 256)   // 391
#define GM 64                     // gemm node tile

typedef float vf4 __attribute__((ext_vector_type(4)));  // clang vector: nt-builtin OK

__device__ __forceinline__ float bf2f(unsigned short u) {
    return __uint_as_float(((unsigned int)u) << 16);
}
__device__ __forceinline__ unsigned short f2bf(float f) {  // RNE
    unsigned int x = __float_as_uint(f);
    return (unsigned short)((x + 0x7fffu + ((x >> 16) & 1u)) >> 16);
}

// ---------------- degree count (also emits per-edge rank) ----------------

__global__ void k_zero(int* __restrict__ cnt) {
    int i = blockIdx.x * 256 + threadIdx.x;
    if (i < NN) cnt[i] = 0;
}

__global__ void k_count(const int* __restrict__ dst, int* __restrict__ cnt,
                        int* __restrict__ pos) {
    int e = blockIdx.x * 256 + threadIdx.x;
    if (e < NE) pos[e] = atomicAdd(&cnt[dst[e]], 1);   // rank within row
}

// ---------------- CSR build: scan (+ norm fused) ----------------

__global__ void k_scan1(const int* __restrict__ cnt, int* __restrict__ rowptr,
                        int* __restrict__ bsum, float* __restrict__ r) {
    __shared__ int sd[256];
    int t = threadIdx.x;
    int i = blockIdx.x * 256 + t;
    int v = (i < NN) ? cnt[i] : 0;
    if (i < NN) r[i] = rsqrtf((float)v + 1.0f);        // fused norm
    sd[t] = v;
    __syncthreads();
#pragma unroll
    for (int off = 1; off < 256; off <<= 1) {
        int x = (t >= off) ? sd[t - off] : 0;
        __syncthreads();
        sd[t] += x;
        __syncthreads();
    }
    if (i < NN) rowptr[i] = sd[t] - v;     // exclusive within block
    if (t == 255) bsum[blockIdx.x] = sd[255];
}

__global__ void k_scan2(int* __restrict__ bsum, int* __restrict__ bscan) {
    __shared__ int sd[512];
    int t = threadIdx.x;
    int v = (t < NBLK) ? bsum[t] : 0;
    sd[t] = v;
    __syncthreads();
#pragma unroll
    for (int off = 1; off < 512; off <<= 1) {
        int x = (t >= off) ? sd[t - off] : 0;
        __syncthreads();
        sd[t] += x;
        __syncthreads();
    }
    bscan[t] = sd[t] - v;
}

__global__ void k_scan3(int* __restrict__ rowptr, const int* __restrict__ bscan) {
    int i = blockIdx.x * 256 + threadIdx.x;
    if (i < NN) rowptr[i] += bscan[blockIdx.x];
    if (i == 0) rowptr[NN] = NE;
}

// pure scatter, no atomic: rank was captured in k_count
__global__ void k_bucket(const int* __restrict__ src, const int* __restrict__ dst,
                         const int* __restrict__ rowptr, const int* __restrict__ pos,
                         int* __restrict__ colidx) {
    int e = blockIdx.x * 256 + threadIdx.x;
    if (e < NE) colidx[rowptr[dst[e]] + pos[e]] = src[e];
}

// ---------------- tiled GEMM: h0 = feat @ W^T + b ----------------

template<bool W16>
__global__ __launch_bounds__(256) void k_gemm(const float* __restrict__ feat,
                                              const float* __restrict__ W,
                                              const float* __restrict__ bias,
                                              const float* __restrict__ r,
                                              float* __restrict__ h0,
                                              float* __restrict__ hinit,
                                              unsigned short* __restrict__ g16) {
    __shared__ float Fl[GM * (IND + 4)];     // 33,792 B
    __shared__ float Wl[OUTD * (IND + 1)];   // 33,024 B
    int t = threadIdx.x;

#pragma unroll
    for (int i = 0; i < 8; ++i) {
        int idx = t + i * 256;
        int o  = idx >> 5;
        int k4 = idx & 31;
        vf4 x = ((const vf4*)W)[idx];
        float* dp = &Wl[o * (IND + 1) + k4 * 4];
        dp[0] = x.x; dp[1] = x.y; dp[2] = x.z; dp[3] = x.w;
    }
    int n0 = blockIdx.x * GM;
#pragma unroll
    for (int i = 0; i < 8; ++i) {
        int idx = t + i * 256;
        int nn = idx >> 5;
        int k4 = idx & 31;
        int n = n0 + nn;
        vf4 x = (vf4)(0.0f);
        if (n < NN) x = __builtin_nontemporal_load(&((const vf4*)feat)[n * 32 + k4]);
        *(vf4*)&Fl[nn * (IND + 4) + k4 * 4] = x;
    }
    __syncthreads();

    int tx = t & 15;
    int ty = t >> 4;
    float acc[4][4];
#pragma unroll
    for (int j = 0; j < 4; ++j)
#pragma unroll
        for (int i = 0; i < 4; ++i) acc[j][i] = 0.f;

    const float* fb = &Fl[(ty * 4) * (IND + 4)];
    const float* wb = &Wl[(tx * 4) * (IND + 1)];
#pragma unroll 8
    for (int k = 0; k < IND; ++k) {
        float a0 = fb[0 * (IND + 4) + k];
        float a1 = fb[1 * (IND + 4) + k];
        float a2 = fb[2 * (IND + 4) + k];
        float a3 = fb[3 * (IND + 4) + k];
        float b0 = wb[0 * (IND + 1) + k];
        float b1 = wb[1 * (IND + 1) + k];
        float b2 = wb[2 * (IND + 1) + k];
        float b3 = wb[3 * (IND + 1) + k];
        acc[0][0] = fmaf(a0, b0, acc[0][0]);
        acc[0][1] = fmaf(a0, b1, acc[0][1]);
        acc[0][2] = fmaf(a0, b2, acc[0][2]);
        acc[0][3] = fmaf(a0, b3, acc[0][3]);
        acc[1][0] = fmaf(a1, b0, acc[1][0]);
        acc[1][1] = fmaf(a1, b1, acc[1][1]);
        acc[1][2] = fmaf(a1, b2, acc[1][2]);
        acc[1][3] = fmaf(a1, b3, acc[1][3]);
        acc[2][0] = fmaf(a2, b0, acc[2][0]);
        acc[2][1] = fmaf(a2, b1, acc[2][1]);
        acc[2][2] = fmaf(a2, b2, acc[2][2]);
        acc[2][3] = fmaf(a2, b3, acc[2][3]);
        acc[3][0] = fmaf(a3, b0, acc[3][0]);
        acc[3][1] = fmaf(a3, b1, acc[3][1]);
        acc[3][2] = fmaf(a3, b2, acc[3][2]);
        acc[3][3] = fmaf(a3, b3, acc[3][3]);
    }

    vf4 bv = ((const vf4*)bias)[tx];
#pragma unroll
    for (int j = 0; j < 4; ++j) {
        int n = n0 + ty * 4 + j;
        if (n < NN) {
            float o0 = acc[j][0] + bv.x;
            float o1 = acc[j][1] + bv.y;
            float o2 = acc[j][2] + bv.z;
            float o3 = acc[j][3] + bv.w;
            float rv = r[n];
            vf4 hh = { o0, o1, o2, o3 };
            __builtin_nontemporal_store(hh, &((vf4*)h0)[n * 16 + tx]);
            float s = rv * rv;
            vf4 hi = { o0 * s, o1 * s, o2 * s, o3 * s };
            __builtin_nontemporal_store(hi, &((vf4*)hinit)[n * 16 + tx]);
            if (W16) {
                uint2 p;
                p.x = (unsigned int)f2bf(o0 * rv) | ((unsigned int)f2bf(o1 * rv) << 16);
                p.y = (unsigned int)f2bf(o2 * rv) | ((unsigned int)f2bf(o3 * rv) << 16);
                ((uint2*)g16)[n * 16 + tx] = p;   // hot next kernel: keep cached
            }
        }
    }
}

// ---------------- propagation: gather-reduce ----------------
// g16[s][c] = bf16(h[s][c] * r[s]); inner loop is a pure add.
// hn[v][c] = 0.5*r[v]*sum_s g[s][c] + 0.5*(h[v][c] + hinit[v][c])

template<bool USE16>
__global__ __launch_bounds__(256) void k_gather(float* __restrict__ hn,
                                                unsigned short* __restrict__ gn16,
                                                const float* __restrict__ h,
                                                const unsigned short* __restrict__ g16,
                                                const float* __restrict__ hinit,
                                                const float* __restrict__ r,
                                                const int* __restrict__ rowptr,
                                                const int* __restrict__ colidx) {
    int t = blockIdx.x * 256 + threadIdx.x;
    int v = t >> 6;
    if (v >= NN) return;
    int c = t & 63;
    int beg = rowptr[v];
    int end = rowptr[v + 1];
    int deg = end - beg;
    int myi = (c < deg) ? colidx[beg + c] : 0;
    int m = deg < 64 ? deg : 64;

    float a0 = 0.f, a1 = 0.f, a2 = 0.f, a3 = 0.f;
    int k = 0;
    for (; k + 3 < m; k += 4) {
        int s0 = __builtin_amdgcn_readlane(myi, k);
        int s1 = __builtin_amdgcn_readlane(myi, k + 1);
        int s2 = __builtin_amdgcn_readlane(myi, k + 2);
        int s3 = __builtin_amdgcn_readlane(myi, k + 3);
        if (USE16) {
            a0 += bf2f(g16[(size_t)s0 * OUTD + c]);
            a1 += bf2f(g16[(size_t)s1 * OUTD + c]);
            a2 += bf2f(g16[(size_t)s2 * OUTD + c]);
            a3 += bf2f(g16[(size_t)s3 * OUTD + c]);
        } else {
            a0 = fmaf(r[s0], h[(size_t)s0 * OUTD + c], a0);
            a1 = fmaf(r[s1], h[(size_t)s1 * OUTD + c], a1);
            a2 = fmaf(r[s2], h[(size_t)s2 * OUTD + c], a2);
            a3 = fmaf(r[s3], h[(size_t)s3 * OUTD + c], a3);
        }
    }
    for (; k < m; ++k) {
        int s = __builtin_amdgcn_readlane(myi, k);
        if (USE16) a0 += bf2f(g16[(size_t)s * OUTD + c]);
        else       a0 = fmaf(r[s], h[(size_t)s * OUTD + c], a0);
    }
    for (int j = beg + 64; j < end; ++j) {       // deg > 64 (rare)
        int s = colidx[j];
        if (USE16) a1 += bf2f(g16[(size_t)s * OUTD + c]);
        else       a1 = fmaf(r[s], h[(size_t)s * OUTD + c], a1);
    }
    float acc = (a0 + a1) + (a2 + a3);
    float rv = r[v];
    // self terms are pure streams: nt loads, nt store for f32 hn
    float hv  = __builtin_nontemporal_load(&h[v * OUTD + c]);
    float hiv = __builtin_nontemporal_load(&hinit[v * OUTD + c]);
    float out = fmaf(0.5f * rv, acc, 0.5f * (hv + hiv));
    __builtin_nontemporal_store(out, &hn[v * OUTD + c]);
    if (USE16) gn16[v * OUTD + c] = f2bf(out * rv);   // hot next step: cached
}

// ---------------- launch ----------------

extern "C" void kernel_launch(void* const* d_in, const int* in_sizes, int n_in,
                              void* d_out, int out_size, void* d_ws, size_t ws_size,
                              hipStream_t stream) {
    const float* feat = (const float*)d_in[0];
    const float* W    = (const float*)d_in[1];
    const float* bias = (const float*)d_in[2];
    const int*   src  = (const int*)d_in[3];
    const int*   dst  = (const int*)d_in[4];

    char* ws = (char*)d_ws;
    int*            cnt    = (int*)(ws + 0);          //   400,000
    float*          rr     = (float*)(ws + 400000);   //   400,000
    int*            rowptr = (int*)(ws + 800000);     //   400,016
    int*            bsum   = (int*)(ws + 1200128);    //     2,048
    int*            bscan  = (int*)(ws + 1202176);    //     2,048
    int*            colidx = (int*)(ws + 1204224);    // 4,000,000
    float*          hA     = (float*)(ws + 5204224);  // 25,600,000
    float*          hinit  = (float*)(ws + 30804224); // 25,600,000
    unsigned short* g16A   = (unsigned short*)(ws + 56404224); // 12,800,000
    unsigned short* g16B   = (unsigned short*)(ws + 69204224); // 12,800,000
    const size_t need16 = 82004224;
    float* h0 = (float*)d_out;
    bool use16 = ws_size >= need16;
    int* pos = (int*)hA;   // alias: dead until first gather writes hA

    k_zero <<<NBLK, 256, 0, stream>>>(cnt);
    k_count<<<(NE + 255) / 256, 256, 0, stream>>>(dst, cnt, pos);

    k_scan1<<<NBLK, 256, 0, stream>>>(cnt, rowptr, bsum, rr);
    k_scan2<<<1, 512, 0, stream>>>(bsum, bscan);
    k_scan3<<<NBLK, 256, 0, stream>>>(rowptr, bscan);
    k_bucket<<<(NE + 255) / 256, 256, 0, stream>>>(src, dst, rowptr, pos, colidx);

    int gemm_blocks = (NN + GM - 1) / GM;   // 1563
    if (use16) {
        k_gemm<true><<<gemm_blocks, 256, 0, stream>>>(feat, W, bias, rr, h0, hinit, g16A);
        unsigned short* b16[2] = { g16A, g16B };
        for (int k = 0; k < KST; ++k) {
            float* hc = (k & 1) ? hA : h0;
            float* hn = (k & 1) ? h0 : hA;
            k_gather<true><<<(NN * 64 + 255) / 256, 256, 0, stream>>>(
                hn, b16[(k & 1) ^ 1], hc, b16[k & 1], hinit, rr, rowptr, colidx);
        }
    } else {
        k_gemm<false><<<gemm_blocks, 256, 0, stream>>>(feat, W, bias, rr, h0, hinit, nullptr);
        for (int k = 0; k < KST; ++k) {
            float* hc = (k & 1) ? hA : h0;
            float* hn = (k & 1) ? h0 : hA;
            k_gather<false><<<(NN * 64 + 255) / 256, 256, 0, stream>>>(
                hn, nullptr, hc, nullptr, hinit, rr, rowptr, colidx);
        }
    }
}

// Round 7
// 339.762 us; speedup vs baseline: 1.0307x; 1.0307x over previous
//
#include <hip/hip_runtime.h>

#define NN 100000
#define NE 1000000
#define IND 128
#define OUTD 64
#define KST 4
#define NBLK ((NN + 255) / 256)   // 391
#define GM 64                     // gemm node tile
#define WS 69                     // packed-LDS row stride (u32): 4*69*tx mod 32 = 20tx -> 2-way max

typedef float vf4 __attribute__((ext_vector_type(4)));  // clang vector: nt-builtin OK

__device__ __forceinline__ float bf2f(unsigned short u) {
    return __uint_as_float(((unsigned int)u) << 16);
}
__device__ __forceinline__ unsigned short f2bf(float f) {  // RNE
    unsigned int x = __float_as_uint(f);
    return (unsigned short)((x + 0x7fffu + ((x >> 16) & 1u)) >> 16);
}
__device__ __forceinline__ unsigned int packbf(float a, float b) {
    return (unsigned int)f2bf(a) | ((unsigned int)f2bf(b) << 16);
}
__device__ __forceinline__ float lo16(unsigned int u) { return __uint_as_float(u << 16); }
__device__ __forceinline__ float hi16(unsigned int u) { return __uint_as_float(u & 0xffff0000u); }

// ---------------- degree count (also emits per-edge rank) ----------------

__global__ void k_zero(int* __restrict__ cnt) {
    int i = blockIdx.x * 256 + threadIdx.x;
    if (i < NN) cnt[i] = 0;
}

__global__ void k_count(const int* __restrict__ dst, int* __restrict__ cnt,
                        int* __restrict__ pos) {
    int e = blockIdx.x * 256 + threadIdx.x;
    if (e < NE) pos[e] = atomicAdd(&cnt[dst[e]], 1);   // rank within row
}

// ---------------- CSR build: scan (+ norm fused) ----------------

__global__ void k_scan1(const int* __restrict__ cnt, int* __restrict__ rowptr,
                        int* __restrict__ bsum, float* __restrict__ r) {
    __shared__ int sd[256];
    int t = threadIdx.x;
    int i = blockIdx.x * 256 + t;
    int v = (i < NN) ? cnt[i] : 0;
    if (i < NN) r[i] = rsqrtf((float)v + 1.0f);        // fused norm
    sd[t] = v;
    __syncthreads();
#pragma unroll
    for (int off = 1; off < 256; off <<= 1) {
        int x = (t >= off) ? sd[t - off] : 0;
        __syncthreads();
        sd[t] += x;
        __syncthreads();
    }
    if (i < NN) rowptr[i] = sd[t] - v;     // exclusive within block
    if (t == 255) bsum[blockIdx.x] = sd[255];
}

__global__ void k_scan2(int* __restrict__ bsum, int* __restrict__ bscan) {
    __shared__ int sd[512];
    int t = threadIdx.x;
    int v = (t < NBLK) ? bsum[t] : 0;
    sd[t] = v;
    __syncthreads();
#pragma unroll
    for (int off = 1; off < 512; off <<= 1) {
        int x = (t >= off) ? sd[t - off] : 0;
        __syncthreads();
        sd[t] += x;
        __syncthreads();
    }
    bscan[t] = sd[t] - v;
}

__global__ void k_scan3(int* __restrict__ rowptr, const int* __restrict__ bscan) {
    int i = blockIdx.x * 256 + threadIdx.x;
    if (i < NN) rowptr[i] += bscan[blockIdx.x];
    if (i == 0) rowptr[NN] = NE;
}

// pure scatter, no atomic: rank was captured in k_count
__global__ void k_bucket(const int* __restrict__ src, const int* __restrict__ dst,
                         const int* __restrict__ rowptr, const int* __restrict__ pos,
                         int* __restrict__ colidx) {
    int e = blockIdx.x * 256 + threadIdx.x;
    if (e < NE) colidx[rowptr[dst[e]] + pos[e]] = src[e];
}

// ---------------- tiled GEMM: h0 = feat @ W^T + b ----------------
// Tiles staged as PACKED bf16 (2/u32): 35.3 KB LDS -> 4 blocks/CU.
// f32 accumulate; k-loop processes 2 k per iteration (1 b32 read = 2 operands).

template<bool W16>
__global__ __launch_bounds__(256, 4) void k_gemm(const float* __restrict__ feat,
                                                 const float* __restrict__ W,
                                                 const float* __restrict__ bias,
                                                 const float* __restrict__ r,
                                                 float* __restrict__ h0,
                                                 float* __restrict__ hinit,
                                                 unsigned short* __restrict__ g16) {
    __shared__ unsigned int Flp[GM * WS];    // 17,664 B
    __shared__ unsigned int Wlp[OUTD * WS];  // 17,664 B
    int t = threadIdx.x;

#pragma unroll
    for (int i = 0; i < 8; ++i) {
        int idx = t + i * 256;
        int o  = idx >> 5;
        int k4 = idx & 31;
        vf4 x = ((const vf4*)W)[idx];
        Wlp[o * WS + 2 * k4]     = packbf(x.x, x.y);
        Wlp[o * WS + 2 * k4 + 1] = packbf(x.z, x.w);
    }
    int n0 = blockIdx.x * GM;
#pragma unroll
    for (int i = 0; i < 8; ++i) {
        int idx = t + i * 256;
        int nn = idx >> 5;
        int k4 = idx & 31;
        int n = n0 + nn;
        vf4 x = (vf4)(0.0f);
        if (n < NN) x = __builtin_nontemporal_load(&((const vf4*)feat)[n * 32 + k4]);
        Flp[nn * WS + 2 * k4]     = packbf(x.x, x.y);
        Flp[nn * WS + 2 * k4 + 1] = packbf(x.z, x.w);
    }
    __syncthreads();

    int tx = t & 15;   // channels 4*tx..4*tx+3
    int ty = t >> 4;   // nodes    4*ty..4*ty+3
    float acc[4][4];
#pragma unroll
    for (int j = 0; j < 4; ++j)
#pragma unroll
        for (int i = 0; i < 4; ++i) acc[j][i] = 0.f;

    const unsigned int* fb = &Flp[(ty * 4) * WS];
    const unsigned int* wb = &Wlp[(tx * 4) * WS];
#pragma unroll 4
    for (int k2 = 0; k2 < IND / 2; ++k2) {
        unsigned int ua0 = fb[0 * WS + k2];
        unsigned int ua1 = fb[1 * WS + k2];
        unsigned int ua2 = fb[2 * WS + k2];
        unsigned int ua3 = fb[3 * WS + k2];
        unsigned int ub0 = wb[0 * WS + k2];
        unsigned int ub1 = wb[1 * WS + k2];
        unsigned int ub2 = wb[2 * WS + k2];
        unsigned int ub3 = wb[3 * WS + k2];
        float ae[4] = { lo16(ua0), lo16(ua1), lo16(ua2), lo16(ua3) };
        float ao[4] = { hi16(ua0), hi16(ua1), hi16(ua2), hi16(ua3) };
        float be[4] = { lo16(ub0), lo16(ub1), lo16(ub2), lo16(ub3) };
        float bo[4] = { hi16(ub0), hi16(ub1), hi16(ub2), hi16(ub3) };
#pragma unroll
        for (int j = 0; j < 4; ++j)
#pragma unroll
            for (int i = 0; i < 4; ++i) {
                acc[j][i] = fmaf(ae[j], be[i], acc[j][i]);
                acc[j][i] = fmaf(ao[j], bo[i], acc[j][i]);
            }
    }

    vf4 bv = ((const vf4*)bias)[tx];
#pragma unroll
    for (int j = 0; j < 4; ++j) {
        int n = n0 + ty * 4 + j;
        if (n < NN) {
            float o0 = acc[j][0] + bv.x;
            float o1 = acc[j][1] + bv.y;
            float o2 = acc[j][2] + bv.z;
            float o3 = acc[j][3] + bv.w;
            float rv = r[n];
            vf4 hh = { o0, o1, o2, o3 };
            __builtin_nontemporal_store(hh, &((vf4*)h0)[n * 16 + tx]);
            float s = rv * rv;
            vf4 hi = { o0 * s, o1 * s, o2 * s, o3 * s };
            __builtin_nontemporal_store(hi, &((vf4*)hinit)[n * 16 + tx]);
            if (W16) {
                uint2 p;
                p.x = packbf(o0 * rv, o1 * rv);
                p.y = packbf(o2 * rv, o3 * rv);
                ((uint2*)g16)[n * 16 + tx] = p;   // hot next kernel: keep cached
            }
        }
    }
}

// ---------------- propagation: gather-reduce ----------------
// g16[s][c] = bf16(h[s][c] * r[s]); inner loop is a pure add.
// hn[v][c] = 0.5*r[v]*sum_s g[s][c] + 0.5*(h[v][c] + hinit[v][c])

template<bool USE16>
__global__ __launch_bounds__(256) void k_gather(float* __restrict__ hn,
                                                unsigned short* __restrict__ gn16,
                                                const float* __restrict__ h,
                                                const unsigned short* __restrict__ g16,
                                                const float* __restrict__ hinit,
                                                const float* __restrict__ r,
                                                const int* __restrict__ rowptr,
                                                const int* __restrict__ colidx) {
    int t = blockIdx.x * 256 + threadIdx.x;
    int v = t >> 6;
    if (v >= NN) return;
    int c = t & 63;
    int beg = rowptr[v];
    int end = rowptr[v + 1];
    int deg = end - beg;
    int myi = (c < deg) ? colidx[beg + c] : 0;
    int m = deg < 64 ? deg : 64;

    float a0 = 0.f, a1 = 0.f, a2 = 0.f, a3 = 0.f;
    int k = 0;
    for (; k + 3 < m; k += 4) {
        int s0 = __builtin_amdgcn_readlane(myi, k);
        int s1 = __builtin_amdgcn_readlane(myi, k + 1);
        int s2 = __builtin_amdgcn_readlane(myi, k + 2);
        int s3 = __builtin_amdgcn_readlane(myi, k + 3);
        if (USE16) {
            a0 += bf2f(g16[(size_t)s0 * OUTD + c]);
            a1 += bf2f(g16[(size_t)s1 * OUTD + c]);
            a2 += bf2f(g16[(size_t)s2 * OUTD + c]);
            a3 += bf2f(g16[(size_t)s3 * OUTD + c]);
        } else {
            a0 = fmaf(r[s0], h[(size_t)s0 * OUTD + c], a0);
            a1 = fmaf(r[s1], h[(size_t)s1 * OUTD + c], a1);
            a2 = fmaf(r[s2], h[(size_t)s2 * OUTD + c], a2);
            a3 = fmaf(r[s3], h[(size_t)s3 * OUTD + c], a3);
        }
    }
    for (; k < m; ++k) {
        int s = __builtin_amdgcn_readlane(myi, k);
        if (USE16) a0 += bf2f(g16[(size_t)s * OUTD + c]);
        else       a0 = fmaf(r[s], h[(size_t)s * OUTD + c], a0);
    }
    for (int j = beg + 64; j < end; ++j) {       // deg > 64 (rare)
        int s = colidx[j];
        if (USE16) a1 += bf2f(g16[(size_t)s * OUTD + c]);
        else       a1 = fmaf(r[s], h[(size_t)s * OUTD + c], a1);
    }
    float acc = (a0 + a1) + (a2 + a3);
    float rv = r[v];
    // self terms are pure streams: nt loads, nt store for f32 hn
    float hv  = __builtin_nontemporal_load(&h[v * OUTD + c]);
    float hiv = __builtin_nontemporal_load(&hinit[v * OUTD + c]);
    float out = fmaf(0.5f * rv, acc, 0.5f * (hv + hiv));
    __builtin_nontemporal_store(out, &hn[v * OUTD + c]);
    if (USE16) gn16[v * OUTD + c] = f2bf(out * rv);   // hot next step: cached
}

// ---------------- launch ----------------

extern "C" void kernel_launch(void* const* d_in, const int* in_sizes, int n_in,
                              void* d_out, int out_size, void* d_ws, size_t ws_size,
                              hipStream_t stream) {
    const float* feat = (const float*)d_in[0];
    const float* W    = (const float*)d_in[1];
    const float* bias = (const float*)d_in[2];
    const int*   src  = (const int*)d_in[3];
    const int*   dst  = (const int*)d_in[4];

    char* ws = (char*)d_ws;
    int*            cnt    = (int*)(ws + 0);          //   400,000
    float*          rr     = (float*)(ws + 400000);   //   400,000
    int*            rowptr = (int*)(ws + 800000);     //   400,016
    int*            bsum   = (int*)(ws + 1200128);    //     2,048
    int*            bscan  = (int*)(ws + 1202176);    //     2,048
    int*            colidx = (int*)(ws + 1204224);    // 4,000,000
    float*          hA     = (float*)(ws + 5204224);  // 25,600,000
    float*          hinit  = (float*)(ws + 30804224); // 25,600,000
    unsigned short* g16A   = (unsigned short*)(ws + 56404224); // 12,800,000
    unsigned short* g16B   = (unsigned short*)(ws + 69204224); // 12,800,000
    const size_t need16 = 82004224;
    float* h0 = (float*)d_out;
    bool use16 = ws_size >= need16;
    int* pos = (int*)hA;   // alias: dead until first gather writes hA

    k_zero <<<NBLK, 256, 0, stream>>>(cnt);
    k_count<<<(NE + 255) / 256, 256, 0, stream>>>(dst, cnt, pos);

    k_scan1<<<NBLK, 256, 0, stream>>>(cnt, rowptr, bsum, rr);
    k_scan2<<<1, 512, 0, stream>>>(bsum, bscan);
    k_scan3<<<NBLK, 256, 0, stream>>>(rowptr, bscan);
    k_bucket<<<(NE + 255) / 256, 256, 0, stream>>>(src, dst, rowptr, pos, colidx);

    int gemm_blocks = (NN + GM - 1) / GM;   // 1563
    if (use16) {
        k_gemm<true><<<gemm_blocks, 256, 0, stream>>>(feat, W, bias, rr, h0, hinit, g16A);
        unsigned short* b16[2] = { g16A, g16B };
        for (int k = 0; k < KST; ++k) {
            float* hc = (k & 1) ? hA : h0;
            float* hn = (k & 1) ? h0 : hA;
            k_gather<true><<<(NN * 64 + 255) / 256, 256, 0, stream>>>(
                hn, b16[(k & 1) ^ 1], hc, b16[k & 1], hinit, rr, rowptr, colidx);
        }
    } else {
        k_gemm<false><<<gemm_blocks, 256, 0, stream>>>(feat, W, bias, rr, h0, hinit, nullptr);
        for (int k = 0; k < KST; ++k) {
            float* hc = (k & 1) ? hA : h0;
            float* hn = (k & 1) ? h0 : hA;
            k_gather<false><<<(NN * 64 + 255) / 256, 256, 0, stream>>>(
                hn, nullptr, hc, nullptr, hinit, rr, rowptr, colidx);
        }
    }
}

// Round 8
// 310.193 us; speedup vs baseline: 1.1290x; 1.0953x over previous
//
#include <hip/hip_runtime.h>

#define NN 100000
#define NE 1000000
#define IND 128
#define OUTD 64
#define KST 4
#define NBLK ((NN + 255) / 256)   // 391
#define GM 64                     // gemm node tile
#define WS 69                     // packed-LDS row stride (u32)

typedef float vf4 __attribute__((ext_vector_type(4)));  // clang vector: nt-builtin OK

__device__ __forceinline__ float bf2f(unsigned short u) {
    return __uint_as_float(((unsigned int)u) << 16);
}
__device__ __forceinline__ unsigned short f2bf(float f) {  // RNE
    unsigned int x = __float_as_uint(f);
    return (unsigned short)((x + 0x7fffu + ((x >> 16) & 1u)) >> 16);
}
__device__ __forceinline__ unsigned int packbf(float a, float b) {
    return (unsigned int)f2bf(a) | ((unsigned int)f2bf(b) << 16);
}
__device__ __forceinline__ float lo16(unsigned int u) { return __uint_as_float(u << 16); }
__device__ __forceinline__ float hi16(unsigned int u) { return __uint_as_float(u & 0xffff0000u); }

// ---------------- degree count (also emits per-edge rank) ----------------

__global__ void k_zero(int* __restrict__ cnt) {
    int i = blockIdx.x * 256 + threadIdx.x;
    if (i < NN) cnt[i] = 0;
}

__global__ void k_count(const int* __restrict__ dst, int* __restrict__ cnt,
                        int* __restrict__ pos) {
    int e = blockIdx.x * 256 + threadIdx.x;
    if (e < NE) pos[e] = atomicAdd(&cnt[dst[e]], 1);   // rank within row
}

// ---------------- CSR build: scan (+ norm fused) ----------------

__global__ void k_scan1(const int* __restrict__ cnt, int* __restrict__ rowptr,
                        int* __restrict__ bsum, float* __restrict__ r) {
    __shared__ int sd[256];
    int t = threadIdx.x;
    int i = blockIdx.x * 256 + t;
    int v = (i < NN) ? cnt[i] : 0;
    if (i < NN) r[i] = rsqrtf((float)v + 1.0f);        // fused norm
    sd[t] = v;
    __syncthreads();
#pragma unroll
    for (int off = 1; off < 256; off <<= 1) {
        int x = (t >= off) ? sd[t - off] : 0;
        __syncthreads();
        sd[t] += x;
        __syncthreads();
    }
    if (i < NN) rowptr[i] = sd[t] - v;     // exclusive within block
    if (t == 255) bsum[blockIdx.x] = sd[255];
}

__global__ void k_scan2(int* __restrict__ bsum, int* __restrict__ bscan) {
    __shared__ int sd[512];
    int t = threadIdx.x;
    int v = (t < NBLK) ? bsum[t] : 0;
    sd[t] = v;
    __syncthreads();
#pragma unroll
    for (int off = 1; off < 512; off <<= 1) {
        int x = (t >= off) ? sd[t - off] : 0;
        __syncthreads();
        sd[t] += x;
        __syncthreads();
    }
    bscan[t] = sd[t] - v;
}

__global__ void k_scan3(int* __restrict__ rowptr, const int* __restrict__ bscan) {
    int i = blockIdx.x * 256 + threadIdx.x;
    if (i < NN) rowptr[i] += bscan[blockIdx.x];
    if (i == 0) rowptr[NN] = NE;
}

// pure scatter, no atomic: rank was captured in k_count
__global__ void k_bucket(const int* __restrict__ src, const int* __restrict__ dst,
                         const int* __restrict__ rowptr, const int* __restrict__ pos,
                         int* __restrict__ colidx) {
    int e = blockIdx.x * 256 + threadIdx.x;
    if (e < NE) colidx[rowptr[dst[e]] + pos[e]] = src[e];
}

// ---------------- tiled GEMM: h0 = feat @ W^T + b ----------------
// Tiles staged as PACKED bf16 (2/u32): 35.3 KB LDS -> 4 blocks/CU.

template<bool W16>
__global__ __launch_bounds__(256, 4) void k_gemm(const float* __restrict__ feat,
                                                 const float* __restrict__ W,
                                                 const float* __restrict__ bias,
                                                 const float* __restrict__ r,
                                                 float* __restrict__ h0,
                                                 float* __restrict__ hinitf,
                                                 unsigned short* __restrict__ hinit16,
                                                 unsigned short* __restrict__ g16) {
    __shared__ unsigned int Flp[GM * WS];    // 17,664 B
    __shared__ unsigned int Wlp[OUTD * WS];  // 17,664 B
    int t = threadIdx.x;

#pragma unroll
    for (int i = 0; i < 8; ++i) {
        int idx = t + i * 256;
        int o  = idx >> 5;
        int k4 = idx & 31;
        vf4 x = ((const vf4*)W)[idx];
        Wlp[o * WS + 2 * k4]     = packbf(x.x, x.y);
        Wlp[o * WS + 2 * k4 + 1] = packbf(x.z, x.w);
    }
    int n0 = blockIdx.x * GM;
#pragma unroll
    for (int i = 0; i < 8; ++i) {
        int idx = t + i * 256;
        int nn = idx >> 5;
        int k4 = idx & 31;
        int n = n0 + nn;
        vf4 x = (vf4)(0.0f);
        if (n < NN) x = __builtin_nontemporal_load(&((const vf4*)feat)[n * 32 + k4]);
        Flp[nn * WS + 2 * k4]     = packbf(x.x, x.y);
        Flp[nn * WS + 2 * k4 + 1] = packbf(x.z, x.w);
    }
    __syncthreads();

    int tx = t & 15;   // channels 4*tx..4*tx+3
    int ty = t >> 4;   // nodes    4*ty..4*ty+3
    float acc[4][4];
#pragma unroll
    for (int j = 0; j < 4; ++j)
#pragma unroll
        for (int i = 0; i < 4; ++i) acc[j][i] = 0.f;

    const unsigned int* fb = &Flp[(ty * 4) * WS];
    const unsigned int* wb = &Wlp[(tx * 4) * WS];
#pragma unroll 4
    for (int k2 = 0; k2 < IND / 2; ++k2) {
        unsigned int ua0 = fb[0 * WS + k2];
        unsigned int ua1 = fb[1 * WS + k2];
        unsigned int ua2 = fb[2 * WS + k2];
        unsigned int ua3 = fb[3 * WS + k2];
        unsigned int ub0 = wb[0 * WS + k2];
        unsigned int ub1 = wb[1 * WS + k2];
        unsigned int ub2 = wb[2 * WS + k2];
        unsigned int ub3 = wb[3 * WS + k2];
        float ae[4] = { lo16(ua0), lo16(ua1), lo16(ua2), lo16(ua3) };
        float ao[4] = { hi16(ua0), hi16(ua1), hi16(ua2), hi16(ua3) };
        float be[4] = { lo16(ub0), lo16(ub1), lo16(ub2), lo16(ub3) };
        float bo[4] = { hi16(ub0), hi16(ub1), hi16(ub2), hi16(ub3) };
#pragma unroll
        for (int j = 0; j < 4; ++j)
#pragma unroll
            for (int i = 0; i < 4; ++i) {
                acc[j][i] = fmaf(ae[j], be[i], acc[j][i]);
                acc[j][i] = fmaf(ao[j], bo[i], acc[j][i]);
            }
    }

    vf4 bv = ((const vf4*)bias)[tx];
#pragma unroll
    for (int j = 0; j < 4; ++j) {
        int n = n0 + ty * 4 + j;
        if (n < NN) {
            float o0 = acc[j][0] + bv.x;
            float o1 = acc[j][1] + bv.y;
            float o2 = acc[j][2] + bv.z;
            float o3 = acc[j][3] + bv.w;
            float rv = r[n];
            vf4 hh = { o0, o1, o2, o3 };
            __builtin_nontemporal_store(hh, &((vf4*)h0)[n * 16 + tx]);
            float s = rv * rv;
            if (W16) {
                uint2 pi;
                pi.x = packbf(o0 * s, o1 * s);
                pi.y = packbf(o2 * s, o3 * s);
                ((uint2*)hinit16)[n * 16 + tx] = pi;
                uint2 p;
                p.x = packbf(o0 * rv, o1 * rv);
                p.y = packbf(o2 * rv, o3 * rv);
                ((uint2*)g16)[n * 16 + tx] = p;   // hot next kernel: keep cached
            } else {
                vf4 hi = { o0 * s, o1 * s, o2 * s, o3 * s };
                __builtin_nontemporal_store(hi, &((vf4*)hinitf)[n * 16 + tx]);
            }
        }
    }
}

// ---------------- propagation: gather-reduce ----------------
// USE16: wave = 1 row; q=lane>>4 edge slot, c4=lane&15 channel group (4 ch).
// Scattered loads are uint2 (4 edges per wave instruction). 2-round butterfly
// combines q-partials; q==0 lanes write.

template<bool USE16, bool FINAL>
__global__ __launch_bounds__(256) void k_gather(float* __restrict__ hn,
                                                unsigned short* __restrict__ gn16,
                                                const float* __restrict__ h,
                                                const unsigned short* __restrict__ g16,
                                                const float* __restrict__ hinitf,
                                                const unsigned short* __restrict__ hinit16,
                                                const float* __restrict__ r,
                                                const int* __restrict__ rowptr,
                                                const int* __restrict__ colidx) {
    int t = blockIdx.x * 256 + threadIdx.x;
    int v = t >> 6;
    if (v >= NN) return;
    int lane = t & 63;
    int beg = rowptr[v];
    int end = rowptr[v + 1];
    int deg = end - beg;
    int m = deg < 64 ? deg : 64;
    int myi = (lane < m) ? colidx[beg + lane] : 0;
    float rv = r[v];

    if (USE16) {
        int q  = lane >> 4;    // edge slot
        int c4 = lane & 15;    // channel group
        float a0 = 0.f, a1 = 0.f, a2 = 0.f, a3 = 0.f;
#pragma unroll 2
        for (int k = 0; k < m; k += 4) {
            int kq = k + q;
            int s = __shfl(myi, kq, 64);     // ds_bpermute: per-lane index ok
            if (kq < m) {
                uint2 u = *(const uint2*)(g16 + (size_t)s * OUTD + 4 * c4);
                a0 += lo16(u.x); a1 += hi16(u.x);
                a2 += lo16(u.y); a3 += hi16(u.y);
            }
        }
        for (int j = beg + 64 + q; j < end; j += 4) {   // deg>64 tail (rare)
            int s = colidx[j];
            uint2 u = *(const uint2*)(g16 + (size_t)s * OUTD + 4 * c4);
            a0 += lo16(u.x); a1 += hi16(u.x);
            a2 += lo16(u.y); a3 += hi16(u.y);
        }
        // combine edge slots (lane bits 4,5)
        a0 += __shfl_xor(a0, 16, 64); a0 += __shfl_xor(a0, 32, 64);
        a1 += __shfl_xor(a1, 16, 64); a1 += __shfl_xor(a1, 32, 64);
        a2 += __shfl_xor(a2, 16, 64); a2 += __shfl_xor(a2, 32, 64);
        a3 += __shfl_xor(a3, 16, 64); a3 += __shfl_xor(a3, 32, 64);

        if (q == 0) {
            vf4 hv = __builtin_nontemporal_load((const vf4*)(h + (size_t)v * OUTD + 4 * c4));
            uint2 iv = *(const uint2*)(hinit16 + (size_t)v * OUTD + 4 * c4);
            float i0 = lo16(iv.x), i1 = hi16(iv.x), i2 = lo16(iv.y), i3 = hi16(iv.y);
            vf4 o;
            o.x = fmaf(0.5f * rv, a0, 0.5f * (hv.x + i0));
            o.y = fmaf(0.5f * rv, a1, 0.5f * (hv.y + i1));
            o.z = fmaf(0.5f * rv, a2, 0.5f * (hv.z + i2));
            o.w = fmaf(0.5f * rv, a3, 0.5f * (hv.w + i3));
            __builtin_nontemporal_store(o, (vf4*)(hn + (size_t)v * OUTD + 4 * c4));
            if (!FINAL) {
                uint2 p;
                p.x = packbf(o.x * rv, o.y * rv);
                p.y = packbf(o.z * rv, o.w * rv);
                *(uint2*)(gn16 + (size_t)v * OUTD + 4 * c4) = p;
            }
        }
    } else {
        // f32 fallback: lane = channel
        int c = lane;
        float a0 = 0.f, a1 = 0.f;
        for (int k = 0; k < m; ++k) {
            int s = __shfl(myi, k, 64);
            a0 = fmaf(r[s], h[(size_t)s * OUTD + c], a0);
        }
        for (int j = beg + 64; j < end; ++j) {
            int s = colidx[j];
            a1 = fmaf(r[s], h[(size_t)s * OUTD + c], a1);
        }
        float acc = a0 + a1;
        float hv  = h[(size_t)v * OUTD + c];
        float hiv = hinitf[(size_t)v * OUTD + c];
        hn[(size_t)v * OUTD + c] = fmaf(0.5f * rv, acc, 0.5f * (hv + hiv));
    }
}

// ---------------- launch ----------------

extern "C" void kernel_launch(void* const* d_in, const int* in_sizes, int n_in,
                              void* d_out, int out_size, void* d_ws, size_t ws_size,
                              hipStream_t stream) {
    const float* feat = (const float*)d_in[0];
    const float* W    = (const float*)d_in[1];
    const float* bias = (const float*)d_in[2];
    const int*   src  = (const int*)d_in[3];
    const int*   dst  = (const int*)d_in[4];

    char* ws = (char*)d_ws;
    int*            cnt    = (int*)(ws + 0);          //   400,000
    float*          rr     = (float*)(ws + 400000);   //   400,000
    int*            rowptr = (int*)(ws + 800000);     //   400,016
    int*            bsum   = (int*)(ws + 1200128);    //     2,048
    int*            bscan  = (int*)(ws + 1202176);    //     2,048
    int*            colidx = (int*)(ws + 1204224);    // 4,000,000
    float*          hA     = (float*)(ws + 5204224);  // 25,600,000
    float*          hinitf = (float*)(ws + 30804224); // 25,600,000 (f32 or bf16 view)
    unsigned short* hinit16= (unsigned short*)hinitf; //  aliased: 12,800,000 used
    unsigned short* g16A   = (unsigned short*)(ws + 56404224); // 12,800,000
    unsigned short* g16B   = (unsigned short*)(ws + 69204224); // 12,800,000
    const size_t need16 = 82004224;
    float* h0 = (float*)d_out;
    bool use16 = ws_size >= need16;
    int* pos = (int*)hA;   // alias: dead until first gather writes hA

    k_zero <<<NBLK, 256, 0, stream>>>(cnt);
    k_count<<<(NE + 255) / 256, 256, 0, stream>>>(dst, cnt, pos);

    k_scan1<<<NBLK, 256, 0, stream>>>(cnt, rowptr, bsum, rr);
    k_scan2<<<1, 512, 0, stream>>>(bsum, bscan);
    k_scan3<<<NBLK, 256, 0, stream>>>(rowptr, bscan);
    k_bucket<<<(NE + 255) / 256, 256, 0, stream>>>(src, dst, rowptr, pos, colidx);

    int gemm_blocks = (NN + GM - 1) / GM;   // 1563
    int gth_blocks  = (NN * 64) / 256;      // 25000
    if (use16) {
        k_gemm<true><<<gemm_blocks, 256, 0, stream>>>(feat, W, bias, rr, h0,
                                                      hinitf, hinit16, g16A);
        k_gather<true, false><<<gth_blocks, 256, 0, stream>>>(
            hA, g16B, h0, g16A, hinitf, hinit16, rr, rowptr, colidx);
        k_gather<true, false><<<gth_blocks, 256, 0, stream>>>(
            h0, g16A, hA, g16B, hinitf, hinit16, rr, rowptr, colidx);
        k_gather<true, false><<<gth_blocks, 256, 0, stream>>>(
            hA, g16B, h0, g16A, hinitf, hinit16, rr, rowptr, colidx);
        k_gather<true, true><<<gth_blocks, 256, 0, stream>>>(
            h0, nullptr, hA, g16B, hinitf, hinit16, rr, rowptr, colidx);
    } else {
        k_gemm<false><<<gemm_blocks, 256, 0, stream>>>(feat, W, bias, rr, h0,
                                                       hinitf, hinit16, nullptr);
        for (int k = 0; k < KST; ++k) {
            float* hc = (k & 1) ? hA : h0;
            float* hn = (k & 1) ? h0 : hA;
            k_gather<false, false><<<gth_blocks, 256, 0, stream>>>(
                hn, nullptr, hc, nullptr, hinitf, hinit16, rr, rowptr, colidx);
        }
    }
}

// Round 9
// 280.331 us; speedup vs baseline: 1.2492x; 1.1065x over previous
//
#include <hip/hip_runtime.h>

#define NN 100000
#define NE 1000000
#define IND 128
#define OUTD 64
#define KST 4
#define NBLK ((NN + 255) / 256)   // 391
#define GM 64                     // gemm node tile

typedef float vf4 __attribute__((ext_vector_type(4)));  // clang vector: nt-builtin OK
typedef short bf8 __attribute__((ext_vector_type(8)));  // 8 bf16 = MFMA A/B frag
typedef unsigned int u32;

__device__ __forceinline__ float bf2f(unsigned short u) {
    return __uint_as_float(((unsigned int)u) << 16);
}
__device__ __forceinline__ unsigned short f2bf(float f) {  // RNE
    unsigned int x = __float_as_uint(f);
    return (unsigned short)((x + 0x7fffu + ((x >> 16) & 1u)) >> 16);
}
__device__ __forceinline__ unsigned int packbf(float a, float b) {
    return (unsigned int)f2bf(a) | ((unsigned int)f2bf(b) << 16);
}
__device__ __forceinline__ float lo16(unsigned int u) { return __uint_as_float(u << 16); }
__device__ __forceinline__ float hi16(unsigned int u) { return __uint_as_float(u & 0xffff0000u); }

// ---------------- degree count (also emits per-edge rank) ----------------

__global__ void k_zero(int* __restrict__ cnt) {
    int i = blockIdx.x * 256 + threadIdx.x;
    if (i < NN) cnt[i] = 0;
}

__global__ void k_count(const int* __restrict__ dst, int* __restrict__ cnt,
                        int* __restrict__ pos) {
    int e = blockIdx.x * 256 + threadIdx.x;
    if (e < NE) pos[e] = atomicAdd(&cnt[dst[e]], 1);   // rank within row
}

// ---------------- CSR build: scan (+ norm fused) ----------------

__global__ void k_scan1(const int* __restrict__ cnt, int* __restrict__ rowptr,
                        int* __restrict__ bsum, float* __restrict__ r) {
    __shared__ int sd[256];
    int t = threadIdx.x;
    int i = blockIdx.x * 256 + t;
    int v = (i < NN) ? cnt[i] : 0;
    if (i < NN) r[i] = rsqrtf((float)v + 1.0f);        // fused norm
    sd[t] = v;
    __syncthreads();
#pragma unroll
    for (int off = 1; off < 256; off <<= 1) {
        int x = (t >= off) ? sd[t - off] : 0;
        __syncthreads();
        sd[t] += x;
        __syncthreads();
    }
    if (i < NN) rowptr[i] = sd[t] - v;     // exclusive within block
    if (t == 255) bsum[blockIdx.x] = sd[255];
}

__global__ void k_scan2(int* __restrict__ bsum, int* __restrict__ bscan) {
    __shared__ int sd[512];
    int t = threadIdx.x;
    int v = (t < NBLK) ? bsum[t] : 0;
    sd[t] = v;
    __syncthreads();
#pragma unroll
    for (int off = 1; off < 512; off <<= 1) {
        int x = (t >= off) ? sd[t - off] : 0;
        __syncthreads();
        sd[t] += x;
        __syncthreads();
    }
    bscan[t] = sd[t] - v;
}

__global__ void k_scan3(int* __restrict__ rowptr, const int* __restrict__ bscan) {
    int i = blockIdx.x * 256 + threadIdx.x;
    if (i < NN) rowptr[i] += bscan[blockIdx.x];
    if (i == 0) rowptr[NN] = NE;
}

// pure scatter, no atomic: rank was captured in k_count
__global__ void k_bucket(const int* __restrict__ src, const int* __restrict__ dst,
                         const int* __restrict__ rowptr, const int* __restrict__ pos,
                         int* __restrict__ colidx) {
    int e = blockIdx.x * 256 + threadIdx.x;
    if (e < NE) colidx[rowptr[dst[e]] + pos[e]] = src[e];
}

// ---------------- MFMA GEMM: h0 = feat @ W^T + b ----------------
// 64-node tile, 4 waves (16 nodes each). feat/W staged bf16 in LDS with
// XOR swizzle (16B-unit ^= row&7) applied on BOTH write and read.
// Frag layout (m89/m91-verified): A/B row|col=lane&15, k=(lane>>4)*8+j;
// C/D col=lane&15, row=(lane>>4)*4+reg.

template<bool W16>
__global__ __launch_bounds__(256) void k_gemm(const float* __restrict__ feat,
                                              const float* __restrict__ W,
                                              const float* __restrict__ bias,
                                              const float* __restrict__ r,
                                              float* __restrict__ h0,
                                              float* __restrict__ hinitf,
                                              unsigned short* __restrict__ hinit16,
                                              unsigned short* __restrict__ g16) {
    __shared__ u32 Fl[GM * 64];    // 64 rows x 256B bf16 (swizzled), 16 KB
    __shared__ u32 Wl[OUTD * 64];  // 16 KB
    int t = threadIdx.x;
    int n0 = blockIdx.x * GM;

    // stage W (1024 16B chunks)
#pragma unroll
    for (int i = 0; i < 4; ++i) {
        int c = t + i * 256;
        int row = c >> 4, kc8 = c & 15;
        vf4 x0 = ((const vf4*)W)[row * 32 + kc8 * 2];
        vf4 x1 = ((const vf4*)W)[row * 32 + kc8 * 2 + 1];
        uint4 p;
        p.x = packbf(x0.x, x0.y); p.y = packbf(x0.z, x0.w);
        p.z = packbf(x1.x, x1.y); p.w = packbf(x1.z, x1.w);
        *(uint4*)((char*)Wl + row * 256 + ((kc8 ^ (row & 7)) << 4)) = p;
    }
    // stage feat tile
#pragma unroll
    for (int i = 0; i < 4; ++i) {
        int c = t + i * 256;
        int row = c >> 4, kc8 = c & 15;
        int n = n0 + row;
        vf4 x0 = (vf4)(0.0f), x1 = (vf4)(0.0f);
        if (n < NN) {
            x0 = __builtin_nontemporal_load(&((const vf4*)feat)[n * 32 + kc8 * 2]);
            x1 = __builtin_nontemporal_load(&((const vf4*)feat)[n * 32 + kc8 * 2 + 1]);
        }
        uint4 p;
        p.x = packbf(x0.x, x0.y); p.y = packbf(x0.z, x0.w);
        p.z = packbf(x1.x, x1.y); p.w = packbf(x1.z, x1.w);
        *(uint4*)((char*)Fl + row * 256 + ((kc8 ^ (row & 7)) << 4)) = p;
    }
    __syncthreads();

    int lane = t & 63, wv = t >> 6;
    int mrow = lane & 15, q = lane >> 4;
    vf4 acc[4];
#pragma unroll
    for (int ct = 0; ct < 4; ++ct) acc[ct] = (vf4)(0.0f);

    int arow = wv * 16 + mrow;
#pragma unroll
    for (int kc = 0; kc < 4; ++kc) {
        bf8 a = *(const bf8*)((const char*)Fl + arow * 256 +
                              (((kc * 4 + q) ^ (arow & 7)) << 4));
#pragma unroll
        for (int ct = 0; ct < 4; ++ct) {
            int ch = ct * 16 + mrow;
            bf8 b = *(const bf8*)((const char*)Wl + ch * 256 +
                                  (((kc * 4 + q) ^ (ch & 7)) << 4));
            acc[ct] = __builtin_amdgcn_mfma_f32_16x16x32_bf16(a, b, acc[ct], 0, 0, 0);
        }
    }

    float bv[4];
#pragma unroll
    for (int ct = 0; ct < 4; ++ct) bv[ct] = bias[ct * 16 + mrow];

#pragma unroll
    for (int reg = 0; reg < 4; ++reg) {
        int n = n0 + wv * 16 + q * 4 + reg;
        if (n < NN) {
            float rv = r[n];
            float s = rv * rv;
#pragma unroll
            for (int ct = 0; ct < 4; ++ct) {
                int ch = ct * 16 + mrow;
                float o = acc[ct][reg] + bv[ct];
                h0[(size_t)n * OUTD + ch] = o;
                if (W16) {
                    g16[(size_t)n * OUTD + ch]     = f2bf(o * rv);
                    hinit16[(size_t)n * OUTD + ch] = f2bf(o * s);
                } else {
                    hinitf[(size_t)n * OUTD + ch] = o * s;
                }
            }
        }
    }
}

// ---------------- propagation: gather-reduce ----------------
// USE16: wave = 1 row; q=lane>>3 edge slot (8), c8=lane&7 channel group (8 ch).
// Scattered loads are uint4 (8 edges per wave instruction). 3-round butterfly
// combines q-partials; q==0 lanes write.

template<bool USE16, bool FINAL>
__global__ __launch_bounds__(256) void k_gather(float* __restrict__ hn,
                                                unsigned short* __restrict__ gn16,
                                                const float* __restrict__ h,
                                                const unsigned short* __restrict__ g16,
                                                const float* __restrict__ hinitf,
                                                const unsigned short* __restrict__ hinit16,
                                                const float* __restrict__ r,
                                                const int* __restrict__ rowptr,
                                                const int* __restrict__ colidx) {
    int t = blockIdx.x * 256 + threadIdx.x;
    int v = t >> 6;
    if (v >= NN) return;
    int lane = t & 63;
    int beg = rowptr[v];
    int end = rowptr[v + 1];
    int deg = end - beg;
    int m = deg < 64 ? deg : 64;
    int myi = (lane < m) ? colidx[beg + lane] : 0;
    float rv = r[v];

    if (USE16) {
        int q  = lane >> 3;    // edge slot
        int c8 = lane & 7;     // channel group (8 ch)
        float a[8] = {0.f, 0.f, 0.f, 0.f, 0.f, 0.f, 0.f, 0.f};
        for (int k = 0; k < m; k += 8) {
            int kq = k + q;
            int s = __shfl(myi, kq, 64);
            if (kq < m) {
                uint4 u = *(const uint4*)(g16 + (size_t)s * OUTD + 8 * c8);
                a[0] += lo16(u.x); a[1] += hi16(u.x);
                a[2] += lo16(u.y); a[3] += hi16(u.y);
                a[4] += lo16(u.z); a[5] += hi16(u.z);
                a[6] += lo16(u.w); a[7] += hi16(u.w);
            }
        }
        for (int j = beg + 64 + q; j < end; j += 8) {   // deg>64 tail (rare)
            int s = colidx[j];
            uint4 u = *(const uint4*)(g16 + (size_t)s * OUTD + 8 * c8);
            a[0] += lo16(u.x); a[1] += hi16(u.x);
            a[2] += lo16(u.y); a[3] += hi16(u.y);
            a[4] += lo16(u.z); a[5] += hi16(u.z);
            a[6] += lo16(u.w); a[7] += hi16(u.w);
        }
        // combine edge slots (lane bits 3,4,5)
#pragma unroll
        for (int i = 0; i < 8; ++i) {
            a[i] += __shfl_xor(a[i], 8, 64);
            a[i] += __shfl_xor(a[i], 16, 64);
            a[i] += __shfl_xor(a[i], 32, 64);
        }

        if (q == 0) {
            size_t base = (size_t)v * OUTD + 8 * c8;
            vf4 hv0 = __builtin_nontemporal_load((const vf4*)(h + base));
            vf4 hv1 = __builtin_nontemporal_load((const vf4*)(h + base + 4));
            uint4 iv = *(const uint4*)(hinit16 + base);
            float i0 = lo16(iv.x), i1 = hi16(iv.x), i2 = lo16(iv.y), i3 = hi16(iv.y);
            float i4 = lo16(iv.z), i5 = hi16(iv.z), i6 = lo16(iv.w), i7 = hi16(iv.w);
            float hr = 0.5f * rv;
            vf4 o0, o1;
            o0.x = fmaf(hr, a[0], 0.5f * (hv0.x + i0));
            o0.y = fmaf(hr, a[1], 0.5f * (hv0.y + i1));
            o0.z = fmaf(hr, a[2], 0.5f * (hv0.z + i2));
            o0.w = fmaf(hr, a[3], 0.5f * (hv0.w + i3));
            o1.x = fmaf(hr, a[4], 0.5f * (hv1.x + i4));
            o1.y = fmaf(hr, a[5], 0.5f * (hv1.y + i5));
            o1.z = fmaf(hr, a[6], 0.5f * (hv1.z + i6));
            o1.w = fmaf(hr, a[7], 0.5f * (hv1.w + i7));
            __builtin_nontemporal_store(o0, (vf4*)(hn + base));
            __builtin_nontemporal_store(o1, (vf4*)(hn + base + 4));
            if (!FINAL) {
                uint4 p;
                p.x = packbf(o0.x * rv, o0.y * rv);
                p.y = packbf(o0.z * rv, o0.w * rv);
                p.z = packbf(o1.x * rv, o1.y * rv);
                p.w = packbf(o1.z * rv, o1.w * rv);
                *(uint4*)(gn16 + base) = p;
            }
        }
    } else {
        // f32 fallback: lane = channel
        int c = lane;
        float a0 = 0.f, a1 = 0.f;
        for (int k = 0; k < m; ++k) {
            int s = __shfl(myi, k, 64);
            a0 = fmaf(r[s], h[(size_t)s * OUTD + c], a0);
        }
        for (int j = beg + 64; j < end; ++j) {
            int s = colidx[j];
            a1 = fmaf(r[s], h[(size_t)s * OUTD + c], a1);
        }
        float acc = a0 + a1;
        float hv  = h[(size_t)v * OUTD + c];
        float hiv = hinitf[(size_t)v * OUTD + c];
        hn[(size_t)v * OUTD + c] = fmaf(0.5f * rv, acc, 0.5f * (hv + hiv));
    }
}

// ---------------- launch ----------------

extern "C" void kernel_launch(void* const* d_in, const int* in_sizes, int n_in,
                              void* d_out, int out_size, void* d_ws, size_t ws_size,
                              hipStream_t stream) {
    const float* feat = (const float*)d_in[0];
    const float* W    = (const float*)d_in[1];
    const float* bias = (const float*)d_in[2];
    const int*   src  = (const int*)d_in[3];
    const int*   dst  = (const int*)d_in[4];

    char* ws = (char*)d_ws;
    int*            cnt    = (int*)(ws + 0);          //   400,000
    float*          rr     = (float*)(ws + 400000);   //   400,000
    int*            rowptr = (int*)(ws + 800000);     //   400,016
    int*            bsum   = (int*)(ws + 1200128);    //     2,048
    int*            bscan  = (int*)(ws + 1202176);    //     2,048
    int*            colidx = (int*)(ws + 1204224);    // 4,000,000
    float*          hA     = (float*)(ws + 5204224);  // 25,600,000
    float*          hinitf = (float*)(ws + 30804224); // 25,600,000 (f32 or bf16 view)
    unsigned short* hinit16= (unsigned short*)hinitf; //  aliased: 12,800,000 used
    unsigned short* g16A   = (unsigned short*)(ws + 56404224); // 12,800,000
    unsigned short* g16B   = (unsigned short*)(ws + 69204224); // 12,800,000
    const size_t need16 = 82004224;
    float* h0 = (float*)d_out;
    bool use16 = ws_size >= need16;
    int* pos = (int*)hA;   // alias: dead until first gather writes hA

    k_zero <<<NBLK, 256, 0, stream>>>(cnt);
    k_count<<<(NE + 255) / 256, 256, 0, stream>>>(dst, cnt, pos);

    k_scan1<<<NBLK, 256, 0, stream>>>(cnt, rowptr, bsum, rr);
    k_scan2<<<1, 512, 0, stream>>>(bsum, bscan);
    k_scan3<<<NBLK, 256, 0, stream>>>(rowptr, bscan);
    k_bucket<<<(NE + 255) / 256, 256, 0, stream>>>(src, dst, rowptr, pos, colidx);

    int gemm_blocks = (NN + GM - 1) / GM;   // 1563
    int gth_blocks  = (NN * 64) / 256;      // 25000
    if (use16) {
        k_gemm<true><<<gemm_blocks, 256, 0, stream>>>(feat, W, bias, rr, h0,
                                                      hinitf, hinit16, g16A);
        k_gather<true, false><<<gth_blocks, 256, 0, stream>>>(
            hA, g16B, h0, g16A, hinitf, hinit16, rr, rowptr, colidx);
        k_gather<true, false><<<gth_blocks, 256, 0, stream>>>(
            h0, g16A, hA, g16B, hinitf, hinit16, rr, rowptr, colidx);
        k_gather<true, false><<<gth_blocks, 256, 0, stream>>>(
            hA, g16B, h0, g16A, hinitf, hinit16, rr, rowptr, colidx);
        k_gather<true, true><<<gth_blocks, 256, 0, stream>>>(
            h0, nullptr, hA, g16B, hinitf, hinit16, rr, rowptr, colidx);
    } else {
        k_gemm<false><<<gemm_blocks, 256, 0, stream>>>(feat, W, bias, rr, h0,
                                                       hinitf, hinit16, nullptr);
        for (int k = 0; k < KST; ++k) {
            float* hc = (k & 1) ? hA : h0;
            float* hn = (k & 1) ? h0 : hA;
            k_gather<false, false><<<gth_blocks, 256, 0, stream>>>(
                hn, nullptr, hc, nullptr, hinitf, hinit16, rr, rowptr, colidx);
        }
    }
}

// Round 10
// 246.485 us; speedup vs baseline: 1.4208x; 1.1373x over previous
//
#include <hip/hip_runtime.h>

#define NN 100000
#define NE 1000000
#define IND 128
#define OUTD 64
#define KST 4
#define NBLK ((NN + 255) / 256)   // 391
#define GM 64                     // gemm node tile

typedef float vf4 __attribute__((ext_vector_type(4)));  // clang vector: nt-builtin OK
typedef short bf8 __attribute__((ext_vector_type(8)));  // 8 bf16 = MFMA A/B frag
typedef unsigned int u32;

__device__ __forceinline__ float bf2f(unsigned short u) {
    return __uint_as_float(((unsigned int)u) << 16);
}
__device__ __forceinline__ unsigned short f2bf(float f) {  // RNE
    unsigned int x = __float_as_uint(f);
    return (unsigned short)((x + 0x7fffu + ((x >> 16) & 1u)) >> 16);
}
__device__ __forceinline__ unsigned int packbf(float a, float b) {
    return (unsigned int)f2bf(a) | ((unsigned int)f2bf(b) << 16);
}
__device__ __forceinline__ float lo16(unsigned int u) { return __uint_as_float(u << 16); }
__device__ __forceinline__ float hi16(unsigned int u) { return __uint_as_float(u & 0xffff0000u); }

// ---------------- degree count (also emits per-edge rank) ----------------

__global__ void k_zero(int* __restrict__ cnt) {
    int i = blockIdx.x * 256 + threadIdx.x;
    if (i < NN) cnt[i] = 0;
}

__global__ void k_count(const int* __restrict__ dst, int* __restrict__ cnt,
                        int* __restrict__ pos) {
    int e = blockIdx.x * 256 + threadIdx.x;
    if (e < NE) pos[e] = atomicAdd(&cnt[dst[e]], 1);   // rank within row
}

// ---------------- CSR build: scan (+ norm fused) ----------------

__global__ void k_scan1(const int* __restrict__ cnt, int* __restrict__ rowptr,
                        int* __restrict__ bsum, float* __restrict__ r) {
    __shared__ int sd[256];
    int t = threadIdx.x;
    int i = blockIdx.x * 256 + t;
    int v = (i < NN) ? cnt[i] : 0;
    if (i < NN) r[i] = rsqrtf((float)v + 1.0f);        // fused norm
    sd[t] = v;
    __syncthreads();
#pragma unroll
    for (int off = 1; off < 256; off <<= 1) {
        int x = (t >= off) ? sd[t - off] : 0;
        __syncthreads();
        sd[t] += x;
        __syncthreads();
    }
    if (i < NN) rowptr[i] = sd[t] - v;     // exclusive within block
    if (t == 255) bsum[blockIdx.x] = sd[255];
}

__global__ void k_scan2(int* __restrict__ bsum, int* __restrict__ bscan) {
    __shared__ int sd[512];
    int t = threadIdx.x;
    int v = (t < NBLK) ? bsum[t] : 0;
    sd[t] = v;
    __syncthreads();
#pragma unroll
    for (int off = 1; off < 512; off <<= 1) {
        int x = (t >= off) ? sd[t - off] : 0;
        __syncthreads();
        sd[t] += x;
        __syncthreads();
    }
    bscan[t] = sd[t] - v;
}

__global__ void k_scan3(int* __restrict__ rowptr, const int* __restrict__ bscan) {
    int i = blockIdx.x * 256 + threadIdx.x;
    if (i < NN) rowptr[i] += bscan[blockIdx.x];
    if (i == 0) rowptr[NN] = NE;
}

// pure scatter, no atomic: rank was captured in k_count
__global__ void k_bucket(const int* __restrict__ src, const int* __restrict__ dst,
                         const int* __restrict__ rowptr, const int* __restrict__ pos,
                         int* __restrict__ colidx) {
    int e = blockIdx.x * 256 + threadIdx.x;
    if (e < NE) colidx[rowptr[dst[e]] + pos[e]] = src[e];
}

// ---------------- MFMA GEMM: h0 = feat @ W^T + b ----------------
// 64-node tile, 4 waves (16 nodes each). feat/W staged bf16 in LDS with
// XOR swizzle (16B-unit ^= row&7) applied on BOTH write and read.

template<bool W16>
__global__ __launch_bounds__(256) void k_gemm(const float* __restrict__ feat,
                                              const float* __restrict__ W,
                                              const float* __restrict__ bias,
                                              const float* __restrict__ r,
                                              float* __restrict__ h0,
                                              float* __restrict__ hinitf,
                                              unsigned short* __restrict__ hinit16,
                                              unsigned short* __restrict__ g16) {
    __shared__ u32 Fl[GM * 64];    // 64 rows x 256B bf16 (swizzled), 16 KB
    __shared__ u32 Wl[OUTD * 64];  // 16 KB
    int t = threadIdx.x;
    int n0 = blockIdx.x * GM;

    // stage W (1024 16B chunks)
#pragma unroll
    for (int i = 0; i < 4; ++i) {
        int c = t + i * 256;
        int row = c >> 4, kc8 = c & 15;
        vf4 x0 = ((const vf4*)W)[row * 32 + kc8 * 2];
        vf4 x1 = ((const vf4*)W)[row * 32 + kc8 * 2 + 1];
        uint4 p;
        p.x = packbf(x0.x, x0.y); p.y = packbf(x0.z, x0.w);
        p.z = packbf(x1.x, x1.y); p.w = packbf(x1.z, x1.w);
        *(uint4*)((char*)Wl + row * 256 + ((kc8 ^ (row & 7)) << 4)) = p;
    }
    // stage feat tile
#pragma unroll
    for (int i = 0; i < 4; ++i) {
        int c = t + i * 256;
        int row = c >> 4, kc8 = c & 15;
        int n = n0 + row;
        vf4 x0 = (vf4)(0.0f), x1 = (vf4)(0.0f);
        if (n < NN) {
            x0 = __builtin_nontemporal_load(&((const vf4*)feat)[n * 32 + kc8 * 2]);
            x1 = __builtin_nontemporal_load(&((const vf4*)feat)[n * 32 + kc8 * 2 + 1]);
        }
        uint4 p;
        p.x = packbf(x0.x, x0.y); p.y = packbf(x0.z, x0.w);
        p.z = packbf(x1.x, x1.y); p.w = packbf(x1.z, x1.w);
        *(uint4*)((char*)Fl + row * 256 + ((kc8 ^ (row & 7)) << 4)) = p;
    }
    __syncthreads();

    int lane = t & 63, wv = t >> 6;
    int mrow = lane & 15, q = lane >> 4;
    vf4 acc[4];
#pragma unroll
    for (int ct = 0; ct < 4; ++ct) acc[ct] = (vf4)(0.0f);

    int arow = wv * 16 + mrow;
#pragma unroll
    for (int kc = 0; kc < 4; ++kc) {
        bf8 a = *(const bf8*)((const char*)Fl + arow * 256 +
                              (((kc * 4 + q) ^ (arow & 7)) << 4));
#pragma unroll
        for (int ct = 0; ct < 4; ++ct) {
            int ch = ct * 16 + mrow;
            bf8 b = *(const bf8*)((const char*)Wl + ch * 256 +
                                  (((kc * 4 + q) ^ (ch & 7)) << 4));
            acc[ct] = __builtin_amdgcn_mfma_f32_16x16x32_bf16(a, b, acc[ct], 0, 0, 0);
        }
    }

    float bv[4];
#pragma unroll
    for (int ct = 0; ct < 4; ++ct) bv[ct] = bias[ct * 16 + mrow];

#pragma unroll
    for (int reg = 0; reg < 4; ++reg) {
        int n = n0 + wv * 16 + q * 4 + reg;
        if (n < NN) {
            float rv = r[n];
            float s = rv * rv;
#pragma unroll
            for (int ct = 0; ct < 4; ++ct) {
                int ch = ct * 16 + mrow;
                float o = acc[ct][reg] + bv[ct];
                h0[(size_t)n * OUTD + ch] = o;
                if (W16) {
                    g16[(size_t)n * OUTD + ch]     = f2bf(o * rv);
                    hinit16[(size_t)n * OUTD + ch] = f2bf(o * s);
                } else {
                    hinitf[(size_t)n * OUTD + ch] = o * s;
                }
            }
        }
    }
}

// ---------------- propagation: gather-reduce ----------------
// USE16: wave = 8 NODES x 8 channel-groups. Lane (q=lane>>3, c8=lane&7) owns
// node v0+q, channels [8*c8, 8*c8+8): accumulates that node's whole edge list
// serially. NO cross-lane reduction, no idle-lane epilogue. Loop bound =
// wave-max degree (3 one-time shfl_xor); k,k+1 independent -> ILP.

template<bool USE16, bool FINAL>
__global__ __launch_bounds__(256) void k_gather(float* __restrict__ hn,
                                                unsigned short* __restrict__ gn16,
                                                const float* __restrict__ h,
                                                const unsigned short* __restrict__ g16,
                                                const float* __restrict__ hinitf,
                                                const unsigned short* __restrict__ hinit16,
                                                const float* __restrict__ r,
                                                const int* __restrict__ rowptr,
                                                const int* __restrict__ colidx) {
    int t = blockIdx.x * 256 + threadIdx.x;
    if (USE16) {
        int wave = t >> 6;
        int lane = t & 63;
        int q  = lane >> 3;    // node slot
        int c8 = lane & 7;     // channel group
        int v = wave * 8 + q;
        bool valid = v < NN;
        int vc = valid ? v : NN - 1;
        int beg = rowptr[vc];
        int deg = rowptr[vc + 1] - beg;
        if (!valid) deg = 0;
        int md = deg;
        md = max(md, __shfl_xor(md, 8, 64));
        md = max(md, __shfl_xor(md, 16, 64));
        md = max(md, __shfl_xor(md, 32, 64));

        float a0 = 0.f, a1 = 0.f, a2 = 0.f, a3 = 0.f;
        float a4 = 0.f, a5 = 0.f, a6 = 0.f, a7 = 0.f;
#pragma unroll 2
        for (int k = 0; k < md; ++k) {
            if (k < deg) {
                int s = colidx[beg + k];
                uint4 u = *(const uint4*)(g16 + (size_t)s * OUTD + 8 * c8);
                a0 += lo16(u.x); a1 += hi16(u.x);
                a2 += lo16(u.y); a3 += hi16(u.y);
                a4 += lo16(u.z); a5 += hi16(u.z);
                a6 += lo16(u.w); a7 += hi16(u.w);
            }
        }

        if (valid) {
            float rv = r[v];
            size_t base = (size_t)v * OUTD + 8 * c8;
            vf4 hv0 = __builtin_nontemporal_load((const vf4*)(h + base));
            vf4 hv1 = __builtin_nontemporal_load((const vf4*)(h + base + 4));
            uint4 iv = *(const uint4*)(hinit16 + base);
            float hr = 0.5f * rv;
            vf4 o0, o1;
            o0.x = fmaf(hr, a0, 0.5f * (hv0.x + lo16(iv.x)));
            o0.y = fmaf(hr, a1, 0.5f * (hv0.y + hi16(iv.x)));
            o0.z = fmaf(hr, a2, 0.5f * (hv0.z + lo16(iv.y)));
            o0.w = fmaf(hr, a3, 0.5f * (hv0.w + hi16(iv.y)));
            o1.x = fmaf(hr, a4, 0.5f * (hv1.x + lo16(iv.z)));
            o1.y = fmaf(hr, a5, 0.5f * (hv1.y + hi16(iv.z)));
            o1.z = fmaf(hr, a6, 0.5f * (hv1.z + lo16(iv.w)));
            o1.w = fmaf(hr, a7, 0.5f * (hv1.w + hi16(iv.w)));
            __builtin_nontemporal_store(o0, (vf4*)(hn + base));
            __builtin_nontemporal_store(o1, (vf4*)(hn + base + 4));
            if (!FINAL) {
                uint4 p;
                p.x = packbf(o0.x * rv, o0.y * rv);
                p.y = packbf(o0.z * rv, o0.w * rv);
                p.z = packbf(o1.x * rv, o1.y * rv);
                p.w = packbf(o1.z * rv, o1.w * rv);
                *(uint4*)(gn16 + base) = p;
            }
        }
    } else {
        // f32 fallback: wave per node, lane = channel
        int v = t >> 6;
        if (v >= NN) return;
        int c = t & 63;
        int beg = rowptr[v];
        int end = rowptr[v + 1];
        float acc = 0.f;
        for (int j = beg; j < end; ++j) {
            int s = colidx[j];
            acc = fmaf(r[s], h[(size_t)s * OUTD + c], acc);
        }
        float rv = r[v];
        float hv  = h[(size_t)v * OUTD + c];
        float hiv = hinitf[(size_t)v * OUTD + c];
        hn[(size_t)v * OUTD + c] = fmaf(0.5f * rv, acc, 0.5f * (hv + hiv));
    }
}

// ---------------- launch ----------------

extern "C" void kernel_launch(void* const* d_in, const int* in_sizes, int n_in,
                              void* d_out, int out_size, void* d_ws, size_t ws_size,
                              hipStream_t stream) {
    const float* feat = (const float*)d_in[0];
    const float* W    = (const float*)d_in[1];
    const float* bias = (const float*)d_in[2];
    const int*   src  = (const int*)d_in[3];
    const int*   dst  = (const int*)d_in[4];

    char* ws = (char*)d_ws;
    int*            cnt    = (int*)(ws + 0);          //   400,000
    float*          rr     = (float*)(ws + 400000);   //   400,000
    int*            rowptr = (int*)(ws + 800000);     //   400,016
    int*            bsum   = (int*)(ws + 1200128);    //     2,048
    int*            bscan  = (int*)(ws + 1202176);    //     2,048
    int*            colidx = (int*)(ws + 1204224);    // 4,000,000
    float*          hA     = (float*)(ws + 5204224);  // 25,600,000
    float*          hinitf = (float*)(ws + 30804224); // 25,600,000 (f32 or bf16 view)
    unsigned short* hinit16= (unsigned short*)hinitf; //  aliased: 12,800,000 used
    unsigned short* g16A   = (unsigned short*)(ws + 56404224); // 12,800,000
    unsigned short* g16B   = (unsigned short*)(ws + 69204224); // 12,800,000
    const size_t need16 = 82004224;
    float* h0 = (float*)d_out;
    bool use16 = ws_size >= need16;
    int* pos = (int*)hA;   // alias: dead until first gather writes hA

    k_zero <<<NBLK, 256, 0, stream>>>(cnt);
    k_count<<<(NE + 255) / 256, 256, 0, stream>>>(dst, cnt, pos);

    k_scan1<<<NBLK, 256, 0, stream>>>(cnt, rowptr, bsum, rr);
    k_scan2<<<1, 512, 0, stream>>>(bsum, bscan);
    k_scan3<<<NBLK, 256, 0, stream>>>(rowptr, bscan);
    k_bucket<<<(NE + 255) / 256, 256, 0, stream>>>(src, dst, rowptr, pos, colidx);

    int gemm_blocks = (NN + GM - 1) / GM;       // 1563
    if (use16) {
        int gth_blocks = (NN + 31) / 32;        // 8 nodes/wave * 4 waves = 32/block
        k_gemm<true><<<gemm_blocks, 256, 0, stream>>>(feat, W, bias, rr, h0,
                                                      hinitf, hinit16, g16A);
        k_gather<true, false><<<gth_blocks, 256, 0, stream>>>(
            hA, g16B, h0, g16A, hinitf, hinit16, rr, rowptr, colidx);
        k_gather<true, false><<<gth_blocks, 256, 0, stream>>>(
            h0, g16A, hA, g16B, hinitf, hinit16, rr, rowptr, colidx);
        k_gather<true, false><<<gth_blocks, 256, 0, stream>>>(
            hA, g16B, h0, g16A, hinitf, hinit16, rr, rowptr, colidx);
        k_gather<true, true><<<gth_blocks, 256, 0, stream>>>(
            h0, nullptr, hA, g16B, hinitf, hinit16, rr, rowptr, colidx);
    } else {
        int gth_blocks = (NN * 64) / 256;
        k_gemm<false><<<gemm_blocks, 256, 0, stream>>>(feat, W, bias, rr, h0,
                                                       hinitf, hinit16, nullptr);
        for (int k = 0; k < KST; ++k) {
            float* hc = (k & 1) ? hA : h0;
            float* hn = (k & 1) ? h0 : hA;
            k_gather<false, false><<<gth_blocks, 256, 0, stream>>>(
                hn, nullptr, hc, nullptr, hinitf, hinit16, rr, rowptr, colidx);
        }
    }
}

// Round 11
// 222.600 us; speedup vs baseline: 1.5732x; 1.1073x over previous
//
#include <hip/hip_runtime.h>

#define NN 100000
#define NE 1000000
#define IND 128
#define OUTD 64
#define KST 4
#define NBLK ((NN + 255) / 256)   // 391
#define GM 64                     // gemm node tile
#define GEMM_BLKS ((NN + GM - 1) / GM)      // 1563
#define BUCK_BLKS ((NE + 255) / 256)        // 3907
#define FUSE_GRPS 782                       // 2 gemm + 5 bucket per group

typedef float vf4 __attribute__((ext_vector_type(4)));
typedef short bf8 __attribute__((ext_vector_type(8)));  // 8 bf16 = MFMA A/B frag
typedef unsigned int u32;

__device__ __forceinline__ float bf2f(unsigned short u) {
    return __uint_as_float(((unsigned int)u) << 16);
}
__device__ __forceinline__ unsigned short f2bf(float f) {  // RNE
    unsigned int x = __float_as_uint(f);
    return (unsigned short)((x + 0x7fffu + ((x >> 16) & 1u)) >> 16);
}
__device__ __forceinline__ unsigned int packbf(float a, float b) {
    return (unsigned int)f2bf(a) | ((unsigned int)f2bf(b) << 16);
}
__device__ __forceinline__ float lo16(unsigned int u) { return __uint_as_float(u << 16); }
__device__ __forceinline__ float hi16(unsigned int u) { return __uint_as_float(u & 0xffff0000u); }

// ---------------- degree count (also emits per-edge rank) ----------------

__global__ void k_zero(int* __restrict__ cnt) {
    int i = blockIdx.x * 256 + threadIdx.x;
    if (i < NN) cnt[i] = 0;
}

__global__ void k_count(const int* __restrict__ dst, int* __restrict__ cnt,
                        int* __restrict__ pos) {
    int e = blockIdx.x * 256 + threadIdx.x;
    if (e < NE) pos[e] = atomicAdd(&cnt[dst[e]], 1);   // rank within row
}

// ---------------- CSR build: scan (+ norm fused) ----------------

__global__ void k_scan1(const int* __restrict__ cnt, int* __restrict__ rowptr,
                        int* __restrict__ bsum, float* __restrict__ r) {
    __shared__ int sd[256];
    int t = threadIdx.x;
    int i = blockIdx.x * 256 + t;
    int v = (i < NN) ? cnt[i] : 0;
    if (i < NN) r[i] = rsqrtf((float)v + 1.0f);        // fused norm
    sd[t] = v;
    __syncthreads();
#pragma unroll
    for (int off = 1; off < 256; off <<= 1) {
        int x = (t >= off) ? sd[t - off] : 0;
        __syncthreads();
        sd[t] += x;
        __syncthreads();
    }
    if (i < NN) rowptr[i] = sd[t] - v;     // exclusive within block
    if (t == 255) bsum[blockIdx.x] = sd[255];
}

__global__ void k_scan2(int* __restrict__ bsum, int* __restrict__ bscan) {
    __shared__ int sd[512];
    int t = threadIdx.x;
    int v = (t < NBLK) ? bsum[t] : 0;
    sd[t] = v;
    __syncthreads();
#pragma unroll
    for (int off = 1; off < 512; off <<= 1) {
        int x = (t >= off) ? sd[t - off] : 0;
        __syncthreads();
        sd[t] += x;
        __syncthreads();
    }
    bscan[t] = sd[t] - v;
}

__global__ void k_scan3(int* __restrict__ rowptr, const int* __restrict__ bscan) {
    int i = blockIdx.x * 256 + threadIdx.x;
    if (i < NN) rowptr[i] += bscan[blockIdx.x];
    if (i == 0) rowptr[NN] = NE;
}

// ---------------- FUSED: MFMA GEMM (2/7 of blocks) + bucket scatter (5/7) ----
// GEMM: 64-node tile, bf16 LDS tiles w/ XOR swizzle, 16x16x32 MFMA.
// State out: g16 = bf16(h0*r), hinit16 = bf16(h0*r^2). NO f32 h0 write.
// Bucket: colidx[rowptr[dst]+pos] = src (rank precomputed in k_count).

__global__ __launch_bounds__(256) void k_gemm_bucket(
        const float* __restrict__ feat, const float* __restrict__ W,
        const float* __restrict__ bias, const float* __restrict__ r,
        unsigned short* __restrict__ hinit16, unsigned short* __restrict__ g16,
        const int* __restrict__ src, const int* __restrict__ dst,
        const int* __restrict__ rowptr, const int* __restrict__ pos,
        int* __restrict__ colidx) {
    int g = blockIdx.x / 7, m = blockIdx.x % 7;
    if (m >= 2) {                     // ---- bucket part ----
        int b = g * 5 + (m - 2);
        if (b < BUCK_BLKS) {
            int e = b * 256 + threadIdx.x;
            if (e < NE) colidx[rowptr[dst[e]] + pos[e]] = src[e];
        }
        return;
    }
    int gb = g * 2 + m;               // ---- gemm part ----
    if (gb >= GEMM_BLKS) return;

    __shared__ u32 Fl[GM * 64];    // 16 KB swizzled bf16
    __shared__ u32 Wl[OUTD * 64];  // 16 KB
    int t = threadIdx.x;
    int n0 = gb * GM;

#pragma unroll
    for (int i = 0; i < 4; ++i) {
        int c = t + i * 256;
        int row = c >> 4, kc8 = c & 15;
        vf4 x0 = ((const vf4*)W)[row * 32 + kc8 * 2];
        vf4 x1 = ((const vf4*)W)[row * 32 + kc8 * 2 + 1];
        uint4 p;
        p.x = packbf(x0.x, x0.y); p.y = packbf(x0.z, x0.w);
        p.z = packbf(x1.x, x1.y); p.w = packbf(x1.z, x1.w);
        *(uint4*)((char*)Wl + row * 256 + ((kc8 ^ (row & 7)) << 4)) = p;
    }
#pragma unroll
    for (int i = 0; i < 4; ++i) {
        int c = t + i * 256;
        int row = c >> 4, kc8 = c & 15;
        int n = n0 + row;
        vf4 x0 = (vf4)(0.0f), x1 = (vf4)(0.0f);
        if (n < NN) {
            x0 = __builtin_nontemporal_load(&((const vf4*)feat)[n * 32 + kc8 * 2]);
            x1 = __builtin_nontemporal_load(&((const vf4*)feat)[n * 32 + kc8 * 2 + 1]);
        }
        uint4 p;
        p.x = packbf(x0.x, x0.y); p.y = packbf(x0.z, x0.w);
        p.z = packbf(x1.x, x1.y); p.w = packbf(x1.z, x1.w);
        *(uint4*)((char*)Fl + row * 256 + ((kc8 ^ (row & 7)) << 4)) = p;
    }
    __syncthreads();

    int lane = t & 63, wv = t >> 6;
    int mrow = lane & 15, q = lane >> 4;
    vf4 acc[4];
#pragma unroll
    for (int ct = 0; ct < 4; ++ct) acc[ct] = (vf4)(0.0f);

    int arow = wv * 16 + mrow;
#pragma unroll
    for (int kc = 0; kc < 4; ++kc) {
        bf8 a = *(const bf8*)((const char*)Fl + arow * 256 +
                              (((kc * 4 + q) ^ (arow & 7)) << 4));
#pragma unroll
        for (int ct = 0; ct < 4; ++ct) {
            int ch = ct * 16 + mrow;
            bf8 b = *(const bf8*)((const char*)Wl + ch * 256 +
                                  (((kc * 4 + q) ^ (ch & 7)) << 4));
            acc[ct] = __builtin_amdgcn_mfma_f32_16x16x32_bf16(a, b, acc[ct], 0, 0, 0);
        }
    }

    float bv[4];
#pragma unroll
    for (int ct = 0; ct < 4; ++ct) bv[ct] = bias[ct * 16 + mrow];

#pragma unroll
    for (int reg = 0; reg < 4; ++reg) {
        int n = n0 + wv * 16 + q * 4 + reg;
        if (n < NN) {
            float rv = r[n];
            float s = rv * rv;
#pragma unroll
            for (int ct = 0; ct < 4; ++ct) {
                int ch = ct * 16 + mrow;
                float o = acc[ct][reg] + bv[ct];
                g16[(size_t)n * OUTD + ch]     = f2bf(o * rv);
                hinit16[(size_t)n * OUTD + ch] = f2bf(o * s);
            }
        }
    }
}

// ---------------- propagation: bf16-state gather ----------------
// Wave = 8 nodes x 8 channel-groups; lane owns 8 channels of one node.
// State: g16 = bf16(h*r). Self term h = g16[v]/r[v] (exact un-scale).
// out = 0.5*(g_self/r + hinit) + 0.5*r*sum(g_scattered)
// FINAL: write f32 d_out. Else: write g16' = bf16(out*r).

template<bool FINAL>
__global__ __launch_bounds__(256) void k_gather16(
        float* __restrict__ hn, unsigned short* __restrict__ gn16,
        const unsigned short* __restrict__ g16,
        const unsigned short* __restrict__ hinit16,
        const float* __restrict__ r,
        const int* __restrict__ rowptr, const int* __restrict__ colidx) {
    int t = blockIdx.x * 256 + threadIdx.x;
    int wave = t >> 6;
    int lane = t & 63;
    int q  = lane >> 3;    // node slot
    int c8 = lane & 7;     // channel group
    int v = wave * 8 + q;
    bool valid = v < NN;
    int vc = valid ? v : NN - 1;
    int beg = rowptr[vc];
    int deg = rowptr[vc + 1] - beg;
    if (!valid) deg = 0;
    int md = deg;
    md = max(md, __shfl_xor(md, 8, 64));
    md = max(md, __shfl_xor(md, 16, 64));
    md = max(md, __shfl_xor(md, 32, 64));

    float a0 = 0.f, a1 = 0.f, a2 = 0.f, a3 = 0.f;
    float a4 = 0.f, a5 = 0.f, a6 = 0.f, a7 = 0.f;
#pragma unroll 2
    for (int k = 0; k < md; ++k) {
        if (k < deg) {
            int s = colidx[beg + k];
            uint4 u = *(const uint4*)(g16 + (size_t)s * OUTD + 8 * c8);
            a0 += lo16(u.x); a1 += hi16(u.x);
            a2 += lo16(u.y); a3 += hi16(u.y);
            a4 += lo16(u.z); a5 += hi16(u.z);
            a6 += lo16(u.w); a7 += hi16(u.w);
        }
    }

    if (valid) {
        float rv = r[v];
        float ir2 = 0.5f / rv;          // for self un-scale * 0.5
        float hr  = 0.5f * rv;
        size_t base = (size_t)v * OUTD + 8 * c8;
        uint4 gs = *(const uint4*)(g16 + base);
        uint4 iv = *(const uint4*)(hinit16 + base);
        float o0 = fmaf(hr, a0, fmaf(lo16(gs.x), ir2, 0.5f * lo16(iv.x)));
        float o1 = fmaf(hr, a1, fmaf(hi16(gs.x), ir2, 0.5f * hi16(iv.x)));
        float o2 = fmaf(hr, a2, fmaf(lo16(gs.y), ir2, 0.5f * lo16(iv.y)));
        float o3 = fmaf(hr, a3, fmaf(hi16(gs.y), ir2, 0.5f * hi16(iv.y)));
        float o4 = fmaf(hr, a4, fmaf(lo16(gs.z), ir2, 0.5f * lo16(iv.z)));
        float o5 = fmaf(hr, a5, fmaf(hi16(gs.z), ir2, 0.5f * hi16(iv.z)));
        float o6 = fmaf(hr, a6, fmaf(lo16(gs.w), ir2, 0.5f * lo16(iv.w)));
        float o7 = fmaf(hr, a7, fmaf(hi16(gs.w), ir2, 0.5f * hi16(iv.w)));
        if (FINAL) {
            vf4 w0 = { o0, o1, o2, o3 };
            vf4 w1 = { o4, o5, o6, o7 };
            __builtin_nontemporal_store(w0, (vf4*)(hn + base));
            __builtin_nontemporal_store(w1, (vf4*)(hn + base + 4));
        } else {
            uint4 p;
            p.x = packbf(o0 * rv, o1 * rv);
            p.y = packbf(o2 * rv, o3 * rv);
            p.z = packbf(o4 * rv, o5 * rv);
            p.w = packbf(o6 * rv, o7 * rv);
            *(uint4*)(gn16 + base) = p;
        }
    }
}

// ---------------- f32 fallback path (ws too small) ----------------

__global__ __launch_bounds__(256) void k_gemm_f32(const float* __restrict__ feat,
                                                  const float* __restrict__ W,
                                                  const float* __restrict__ bias,
                                                  const float* __restrict__ r,
                                                  float* __restrict__ h0,
                                                  float* __restrict__ hinitf) {
    __shared__ u32 Fl[GM * 64];
    __shared__ u32 Wl[OUTD * 64];
    int t = threadIdx.x;
    int n0 = blockIdx.x * GM;
#pragma unroll
    for (int i = 0; i < 4; ++i) {
        int c = t + i * 256;
        int row = c >> 4, kc8 = c & 15;
        vf4 x0 = ((const vf4*)W)[row * 32 + kc8 * 2];
        vf4 x1 = ((const vf4*)W)[row * 32 + kc8 * 2 + 1];
        uint4 p;
        p.x = packbf(x0.x, x0.y); p.y = packbf(x0.z, x0.w);
        p.z = packbf(x1.x, x1.y); p.w = packbf(x1.z, x1.w);
        *(uint4*)((char*)Wl + row * 256 + ((kc8 ^ (row & 7)) << 4)) = p;
    }
#pragma unroll
    for (int i = 0; i < 4; ++i) {
        int c = t + i * 256;
        int row = c >> 4, kc8 = c & 15;
        int n = n0 + row;
        vf4 x0 = (vf4)(0.0f), x1 = (vf4)(0.0f);
        if (n < NN) {
            x0 = ((const vf4*)feat)[n * 32 + kc8 * 2];
            x1 = ((const vf4*)feat)[n * 32 + kc8 * 2 + 1];
        }
        uint4 p;
        p.x = packbf(x0.x, x0.y); p.y = packbf(x0.z, x0.w);
        p.z = packbf(x1.x, x1.y); p.w = packbf(x1.z, x1.w);
        *(uint4*)((char*)Fl + row * 256 + ((kc8 ^ (row & 7)) << 4)) = p;
    }
    __syncthreads();
    int lane = t & 63, wv = t >> 6;
    int mrow = lane & 15, q = lane >> 4;
    vf4 acc[4];
#pragma unroll
    for (int ct = 0; ct < 4; ++ct) acc[ct] = (vf4)(0.0f);
    int arow = wv * 16 + mrow;
#pragma unroll
    for (int kc = 0; kc < 4; ++kc) {
        bf8 a = *(const bf8*)((const char*)Fl + arow * 256 +
                              (((kc * 4 + q) ^ (arow & 7)) << 4));
#pragma unroll
        for (int ct = 0; ct < 4; ++ct) {
            int ch = ct * 16 + mrow;
            bf8 b = *(const bf8*)((const char*)Wl + ch * 256 +
                                  (((kc * 4 + q) ^ (ch & 7)) << 4));
            acc[ct] = __builtin_amdgcn_mfma_f32_16x16x32_bf16(a, b, acc[ct], 0, 0, 0);
        }
    }
#pragma unroll
    for (int reg = 0; reg < 4; ++reg) {
        int n = n0 + wv * 16 + q * 4 + reg;
        if (n < NN) {
            float rv = r[n];
            float s = rv * rv;
#pragma unroll
            for (int ct = 0; ct < 4; ++ct) {
                int ch = ct * 16 + mrow;
                float o = acc[ct][reg] + bias[ct * 16 + mrow];
                h0[(size_t)n * OUTD + ch]     = o;
                hinitf[(size_t)n * OUTD + ch] = o * s;
            }
        }
    }
}

__global__ void k_bucket(const int* __restrict__ src, const int* __restrict__ dst,
                         const int* __restrict__ rowptr, const int* __restrict__ pos,
                         int* __restrict__ colidx) {
    int e = blockIdx.x * 256 + threadIdx.x;
    if (e < NE) colidx[rowptr[dst[e]] + pos[e]] = src[e];
}

__global__ __launch_bounds__(256) void k_gather_f32(float* __restrict__ hn,
                                                    const float* __restrict__ h,
                                                    const float* __restrict__ hinitf,
                                                    const float* __restrict__ r,
                                                    const int* __restrict__ rowptr,
                                                    const int* __restrict__ colidx) {
    int t = blockIdx.x * 256 + threadIdx.x;
    int v = t >> 6;
    if (v >= NN) return;
    int c = t & 63;
    int beg = rowptr[v];
    int end = rowptr[v + 1];
    float acc = 0.f;
    for (int j = beg; j < end; ++j) {
        int s = colidx[j];
        acc = fmaf(r[s], h[(size_t)s * OUTD + c], acc);
    }
    float rv = r[v];
    float hv  = h[(size_t)v * OUTD + c];
    float hiv = hinitf[(size_t)v * OUTD + c];
    hn[(size_t)v * OUTD + c] = fmaf(0.5f * rv, acc, 0.5f * (hv + hiv));
}

// ---------------- launch ----------------

extern "C" void kernel_launch(void* const* d_in, const int* in_sizes, int n_in,
                              void* d_out, int out_size, void* d_ws, size_t ws_size,
                              hipStream_t stream) {
    const float* feat = (const float*)d_in[0];
    const float* W    = (const float*)d_in[1];
    const float* bias = (const float*)d_in[2];
    const int*   src  = (const int*)d_in[3];
    const int*   dst  = (const int*)d_in[4];

    char* ws = (char*)d_ws;
    int*            cnt    = (int*)(ws + 0);          //   400,000
    float*          rr     = (float*)(ws + 400000);   //   400,000
    int*            rowptr = (int*)(ws + 800000);     //   400,016
    int*            bsum   = (int*)(ws + 1200128);    //     2,048
    int*            bscan  = (int*)(ws + 1202176);    //     2,048
    int*            colidx = (int*)(ws + 1204224);    // 4,000,000
    float*          hA     = (float*)(ws + 5204224);  // 25,600,000 (pos scratch / f32 ping)
    float*          hinitf = (float*)(ws + 30804224); // 25,600,000 (f32 or bf16 view)
    unsigned short* hinit16= (unsigned short*)hinitf;
    unsigned short* g16A   = (unsigned short*)(ws + 56404224); // 12,800,000
    unsigned short* g16B   = (unsigned short*)(ws + 69204224); // 12,800,000
    const size_t need16 = 82004224;
    float* h0 = (float*)d_out;
    bool use16 = ws_size >= need16;
    int* pos = (int*)hA;   // alias: dead until f32 path's first gather

    k_zero <<<NBLK, 256, 0, stream>>>(cnt);
    k_count<<<BUCK_BLKS, 256, 0, stream>>>(dst, cnt, pos);
    k_scan1<<<NBLK, 256, 0, stream>>>(cnt, rowptr, bsum, rr);
    k_scan2<<<1, 512, 0, stream>>>(bsum, bscan);
    k_scan3<<<NBLK, 256, 0, stream>>>(rowptr, bscan);

    if (use16) {
        k_gemm_bucket<<<FUSE_GRPS * 7, 256, 0, stream>>>(
            feat, W, bias, rr, hinit16, g16A, src, dst, rowptr, pos, colidx);
        int gth_blocks = (NN + 31) / 32;    // 3125
        k_gather16<false><<<gth_blocks, 256, 0, stream>>>(
            nullptr, g16B, g16A, hinit16, rr, rowptr, colidx);
        k_gather16<false><<<gth_blocks, 256, 0, stream>>>(
            nullptr, g16A, g16B, hinit16, rr, rowptr, colidx);
        k_gather16<false><<<gth_blocks, 256, 0, stream>>>(
            nullptr, g16B, g16A, hinit16, rr, rowptr, colidx);
        k_gather16<true><<<gth_blocks, 256, 0, stream>>>(
            (float*)d_out, nullptr, g16B, hinit16, rr, rowptr, colidx);
    } else {
        k_bucket<<<BUCK_BLKS, 256, 0, stream>>>(src, dst, rowptr, pos, colidx);
        k_gemm_f32<<<GEMM_BLKS, 256, 0, stream>>>(feat, W, bias, rr, h0, hinitf);
        int gth_blocks = (NN * 64) / 256;
        for (int k = 0; k < KST; ++k) {
            float* hc = (k & 1) ? hA : h0;
            float* hn = (k & 1) ? h0 : hA;
            k_gather_f32<<<gth_blocks, 256, 0, stream>>>(hn, hc, hinitf, rr,
                                                         rowptr, colidx);
        }
    }
}